// Round 2
// baseline (450.524 us; speedup 1.0000x reference)
//
#include <hip/hip_runtime.h>
#include <math.h>

#define B_ 32
#define T_ 1024
#define D_ 512
#define U_ 64
#define TS_ 4          // t-reduction split in K1
#define TH_ (T_/TS_)   // 256
#define TC_ 32         // K1 t-chunk staged in LDS
#define SR_ 10.0f
#define EPS_ 1e-7f

// ---------------------------------------------------------------------------
// K1: partial combined matrices. For each (b, d-tile of 64, t-quarter):
//   P[ts][b][0][d][u] += sum_t x1[b,t,d]*w3[t,u] + x2[b,t,d]*w2[t,u]   (M1 part)
//   P[ts][b][1][d][u] += sum_t x1[b,t,d]*w2[t,u] + x2[b,t,d]*w3[t,u]   (M2 part)
// 1024 blocks, 32 KiB LDS -> 4+ blocks/CU.
// ---------------------------------------------------------------------------
__global__ __launch_bounds__(256, 4) void k1_partials(
    const float* __restrict__ x1, const float* __restrict__ x2,
    const float* __restrict__ w2, const float* __restrict__ w3,
    float* __restrict__ P)
{
    __shared__ float x1s[TC_*64];
    __shared__ float x2s[TC_*64];
    __shared__ float w2s[TC_*64];
    __shared__ float w3s[TC_*64];

    const int dt  = blockIdx.x;       // 0..7
    const int ts  = blockIdx.y;       // 0..TS_-1
    const int b   = blockIdx.z;       // 0..31
    const int d0  = dt * 64;
    const int tid = threadIdx.x;
    const int td  = tid & 15;         // d = d0 + td*4 + i
    const int tu  = tid >> 4;         // u = tu*4 + j

    float accM1[4][4];
    float accM2[4][4];
    #pragma unroll
    for (int i = 0; i < 4; ++i)
        #pragma unroll
        for (int j = 0; j < 4; ++j) { accM1[i][j] = 0.f; accM2[i][j] = 0.f; }

    const size_t xb = (size_t)b * T_ * D_;

    for (int c = 0; c < TH_/TC_; ++c) {
        const int tb = ts*TH_ + c*TC_;
        #pragma unroll
        for (int j = 0; j < 2; ++j) {
            int l  = j*256 + tid;           // 0..511
            int tl = l >> 4;                // 0..31
            int f  = (l & 15) << 2;         // 0..60
            *(float4*)&x1s[tl*64 + f] = *(const float4*)&x1[xb + (size_t)(tb+tl)*D_ + d0 + f];
            *(float4*)&x2s[tl*64 + f] = *(const float4*)&x2[xb + (size_t)(tb+tl)*D_ + d0 + f];
            *(float4*)&w2s[tl*64 + f] = *(const float4*)&w2[(size_t)(tb+tl)*U_ + f];
            *(float4*)&w3s[tl*64 + f] = *(const float4*)&w3[(size_t)(tb+tl)*U_ + f];
        }
        __syncthreads();
        #pragma unroll 2
        for (int t = 0; t < TC_; ++t) {
            float4 a1 = *(const float4*)&x1s[t*64 + td*4];
            float4 a2 = *(const float4*)&x2s[t*64 + td*4];
            float4 c2 = *(const float4*)&w2s[t*64 + tu*4];
            float4 c3 = *(const float4*)&w3s[t*64 + tu*4];
            float a1v[4] = {a1.x,a1.y,a1.z,a1.w};
            float a2v[4] = {a2.x,a2.y,a2.z,a2.w};
            float c2v[4] = {c2.x,c2.y,c2.z,c2.w};
            float c3v[4] = {c3.x,c3.y,c3.z,c3.w};
            #pragma unroll
            for (int i = 0; i < 4; ++i)
                #pragma unroll
                for (int j = 0; j < 4; ++j) {
                    accM1[i][j] += a1v[i]*c3v[j] + a2v[i]*c2v[j];
                    accM2[i][j] += a1v[i]*c2v[j] + a2v[i]*c3v[j];
                }
        }
        __syncthreads();
    }

    const size_t DU = (size_t)D_ * U_;
    #pragma unroll
    for (int i = 0; i < 4; ++i) {
        size_t base = (((size_t)ts*B_ + b)*2)*DU + (size_t)(d0 + td*4 + i)*U_ + tu*4;
        float4 v1 = {accM1[i][0], accM1[i][1], accM1[i][2], accM1[i][3]};
        float4 v2 = {accM2[i][0], accM2[i][1], accM2[i][2], accM2[i][3]};
        *(float4*)&P[base]      = v1;
        *(float4*)&P[base + DU] = v2;
    }
}

// ---------------------------------------------------------------------------
// K1b: M1 = w1 + sum_ts P[ts][b][0];  M2 = w1 + sum_ts P[ts][b][1]
// ---------------------------------------------------------------------------
__global__ __launch_bounds__(256) void k1_combine(
    const float* __restrict__ P, const float* __restrict__ w1,
    float* __restrict__ M1, float* __restrict__ M2)
{
    const int n = blockIdx.x*256 + threadIdx.x;   // 0 .. B*D*U/4-1
    const int b = n >> 13;                        // D*U/4 = 8192
    const int r = n & 8191;
    const size_t du = (size_t)r * 4;
    const size_t DU = (size_t)D_ * U_;
    float4 w = *(const float4*)&w1[du];
    float4 s1 = w, s2 = w;
    #pragma unroll
    for (int ts = 0; ts < TS_; ++ts) {
        const float* Pb = P + (((size_t)ts*B_ + b)*2)*DU + du;
        float4 a = *(const float4*)&Pb[0];
        float4 c = *(const float4*)&Pb[DU];
        s1.x += a.x; s1.y += a.y; s1.z += a.z; s1.w += a.w;
        s2.x += c.x; s2.y += c.y; s2.z += c.z; s2.w += c.w;
    }
    *(float4*)&M1[(size_t)b*DU + du] = s1;
    *(float4*)&M2[(size_t)b*DU + du] = s2;
}

// ---------------------------------------------------------------------------
// K2: eij[br][b][t] = SR * sum_u tanh( sum_d x[b,t,d]*M[b,d,u] ) * we[u]
// block: (t-tile 64) x (b) x (branch); 256 threads; ~38 KiB LDS -> 4 blk/CU
// ---------------------------------------------------------------------------
#define TT_ 64
#define XPAD_ 69
__global__ __launch_bounds__(256, 4) void k2_eij(
    const float* __restrict__ x1, const float* __restrict__ x2,
    const float* __restrict__ M1, const float* __restrict__ M2,
    const float* __restrict__ we, float* __restrict__ eij)
{
    __shared__ float xT[64*XPAD_];   // [d][t] transposed, padded
    __shared__ float Ms[64*64];      // [d][u]
    __shared__ float wes[64];
    __shared__ float red[16*TT_];

    const int tt = blockIdx.x;       // 0..15
    const int b  = blockIdx.y;       // 0..31
    const int br = blockIdx.z;       // 0..1
    const float* x = br ? x2 : x1;
    const float* M = (br ? M2 : M1) + (size_t)b * D_ * U_;
    const int tid = threadIdx.x;
    const int tdl = tid & 15;        // t = tdl*4 + i
    const int tu  = tid >> 4;        // u = tu*4 + j
    if (tid < 64) wes[tid] = we[tid];

    float acc[4][4];
    #pragma unroll
    for (int i = 0; i < 4; ++i)
        #pragma unroll
        for (int j = 0; j < 4; ++j) acc[i][j] = 0.f;

    const size_t xb = (size_t)b*T_*D_ + (size_t)tt*TT_*D_;

    for (int c = 0; c < D_/64; ++c) {
        #pragma unroll
        for (int j = 0; j < 4; ++j) {
            int l  = j*256 + tid;        // 0..1023
            int tl = l >> 4;             // 0..63
            int f  = (l & 15) << 2;      // 0..60
            float4 v = *(const float4*)&x[xb + (size_t)tl*D_ + c*64 + f];
            xT[(f+0)*XPAD_ + tl] = v.x;
            xT[(f+1)*XPAD_ + tl] = v.y;
            xT[(f+2)*XPAD_ + tl] = v.z;
            xT[(f+3)*XPAD_ + tl] = v.w;
        }
        #pragma unroll
        for (int j = 0; j < 4; ++j) {
            int l  = j*256 + tid;
            int dl = l >> 4;
            int f  = (l & 15) << 2;
            *(float4*)&Ms[dl*64 + f] = *(const float4*)&M[(size_t)(c*64 + dl)*U_ + f];
        }
        __syncthreads();
        #pragma unroll 2
        for (int d = 0; d < 64; ++d) {
            float4 xv = *(const float4*)&xT[d*XPAD_ + tdl*4];
            float4 mv = *(const float4*)&Ms[d*64 + tu*4];
            float xvv[4] = {xv.x,xv.y,xv.z,xv.w};
            float mvv[4] = {mv.x,mv.y,mv.z,mv.w};
            #pragma unroll
            for (int i = 0; i < 4; ++i)
                #pragma unroll
                for (int j = 0; j < 4; ++j)
                    acc[i][j] += xvv[i]*mvv[j];
        }
        __syncthreads();
    }

    #pragma unroll
    for (int i = 0; i < 4; ++i) {
        float p = 0.f;
        #pragma unroll
        for (int j = 0; j < 4; ++j)
            p += tanhf(acc[i][j]) * wes[tu*4 + j];
        red[tu*TT_ + tdl*4 + i] = p;
    }
    __syncthreads();
    if (tid < TT_) {
        float s = 0.f;
        #pragma unroll
        for (int q = 0; q < 16; ++q) s += red[q*TT_ + tid];
        eij[((size_t)br*B_ + b)*T_ + tt*TT_ + tid] = SR_ * s;
    }
}

// ---------------------------------------------------------------------------
// K3: stable softmax over T per (branch,b): ww = exp(e-m)/(sum + eps*exp(-m))
// ---------------------------------------------------------------------------
__global__ __launch_bounds__(256) void k3_softmax(
    const float* __restrict__ eij, float* __restrict__ ww)
{
    __shared__ float sdata[256];
    const int bb  = blockIdx.x;                  // br*B + b, 0..63
    const int tid = threadIdx.x;
    const float* e = eij + (size_t)bb * T_;
    float v[4];
    float m = -1e30f;
    #pragma unroll
    for (int i = 0; i < 4; ++i) { v[i] = e[tid + i*256]; m = fmaxf(m, v[i]); }
    sdata[tid] = m; __syncthreads();
    for (int s = 128; s > 0; s >>= 1) {
        if (tid < s) sdata[tid] = fmaxf(sdata[tid], sdata[tid+s]);
        __syncthreads();
    }
    m = sdata[0]; __syncthreads();
    float ssum = 0.f;
    #pragma unroll
    for (int i = 0; i < 4; ++i) { v[i] = expf(v[i] - m); ssum += v[i]; }
    sdata[tid] = ssum; __syncthreads();
    for (int s = 128; s > 0; s >>= 1) {
        if (tid < s) sdata[tid] += sdata[tid+s];
        __syncthreads();
    }
    float inv = 1.0f / (sdata[0] + EPS_ * expf(-m));
    #pragma unroll
    for (int i = 0; i < 4; ++i) ww[(size_t)bb*T_ + tid + i*256] = v[i] * inv;
}

// ---------------------------------------------------------------------------
// K4: out[br][b,t,d] = x[b,t,d] * ww[br][b][t]
// ---------------------------------------------------------------------------
__global__ __launch_bounds__(256) void k4_scale(
    const float* __restrict__ x1, const float* __restrict__ x2,
    const float* __restrict__ ww, float* __restrict__ out)
{
    const size_t NF4 = (size_t)2*B_*T_*D_/4;     // 8388608
    size_t n = (size_t)blockIdx.x*256 + threadIdx.x;
    const size_t stride = (size_t)gridDim.x*256;
    for (; n < NF4; n += stride) {
        const size_t br = n >> 22;               // / (B*T*D/4)
        const size_t r  = n & ((1u<<22) - 1);
        const size_t bt = r >> 7;                // / (D/4)
        const float* x = br ? x2 : x1;
        float w = ww[br*(size_t)(B_*T_) + bt];
        float4 v = ((const float4*)x)[r];
        float4 o = {v.x*w, v.y*w, v.z*w, v.w*w};
        ((float4*)out)[n] = o;
    }
}

// ---------------------------------------------------------------------------
extern "C" void kernel_launch(void* const* d_in, const int* in_sizes, int n_in,
                              void* d_out, int out_size, void* d_ws, size_t ws_size,
                              hipStream_t stream)
{
    const float* x1 = (const float*)d_in[0];
    const float* x2 = (const float*)d_in[1];
    const float* w1 = (const float*)d_in[2];
    const float* w2 = (const float*)d_in[3];
    const float* w3 = (const float*)d_in[4];
    const float* we = (const float*)d_in[5];
    float* out = (float*)d_out;
    float* ws  = (float*)d_ws;

    // workspace layout (floats)
    float* P   = ws;                             // TS_*B_*2*D_*U_ = 8,388,608
    float* M1  = P   + (size_t)TS_*B_*2*D_*U_;   // 1,048,576
    float* M2  = M1  + (size_t)B_*D_*U_;         // 1,048,576
    float* eij = M2  + (size_t)B_*D_*U_;         // 65,536
    float* wwb = eij + (size_t)2*B_*T_;          // 65,536

    k1_partials<<<dim3(8, TS_, B_), 256, 0, stream>>>(x1, x2, w2, w3, P);
    k1_combine <<<dim3((B_*D_*U_/4 + 255)/256), 256, 0, stream>>>(P, w1, M1, M2);
    k2_eij     <<<dim3(T_/TT_, B_, 2), 256, 0, stream>>>(x1, x2, M1, M2, we, eij);
    k3_softmax <<<dim3(2*B_), 256, 0, stream>>>(eij, wwb);
    k4_scale   <<<dim3(8192), 256, 0, stream>>>(x1, x2, wwb, out);
}

// Round 3
// 400.213 us; speedup vs baseline: 1.1257x; 1.1257x over previous
//
#include <hip/hip_runtime.h>
#include <math.h>

#define B_ 32
#define T_ 1024
#define D_ 512
#define U_ 64
#define TS_ 4          // t-reduction split in K1
#define TH_ (T_/TS_)   // 256
#define TC_ 32         // K1 t-chunk staged in LDS
#define SR_ 10.0f
#define EPS_ 1e-7f

// ---------------------------------------------------------------------------
// K1: partial combined matrices. For each (b, d-tile of 64, t-quarter):
//   P[ts][b][0][d][u] += sum_t x1*w3 + x2*w2   (M1 part)
//   P[ts][b][1][d][u] += sum_t x1*w2 + x2*w3   (M2 part)
// NOTE: accumulation kept as SEPARATE statements so each contracts to v_fma
// (a += x*y + z*w forces mul+fma+add = 1.5x VALU — measured R2 regression).
// ---------------------------------------------------------------------------
__global__ __launch_bounds__(256, 4) void k1_partials(
    const float* __restrict__ x1, const float* __restrict__ x2,
    const float* __restrict__ w2, const float* __restrict__ w3,
    float* __restrict__ P)
{
    __shared__ float x1s[TC_*64];
    __shared__ float x2s[TC_*64];
    __shared__ float w2s[TC_*64];
    __shared__ float w3s[TC_*64];

    const int dt  = blockIdx.x;       // 0..7
    const int ts  = blockIdx.y;       // 0..TS_-1
    const int b   = blockIdx.z;       // 0..31
    const int d0  = dt * 64;
    const int tid = threadIdx.x;
    const int td  = tid & 15;         // d = d0 + td*4 + i
    const int tu  = tid >> 4;         // u = tu*4 + j

    float accM1[4][4];
    float accM2[4][4];
    #pragma unroll
    for (int i = 0; i < 4; ++i)
        #pragma unroll
        for (int j = 0; j < 4; ++j) { accM1[i][j] = 0.f; accM2[i][j] = 0.f; }

    const size_t xb = (size_t)b * T_ * D_;

    for (int c = 0; c < TH_/TC_; ++c) {
        const int tb = ts*TH_ + c*TC_;
        #pragma unroll
        for (int j = 0; j < 2; ++j) {
            int l  = j*256 + tid;           // 0..511
            int tl = l >> 4;                // 0..31
            int f  = (l & 15) << 2;         // 0..60
            *(float4*)&x1s[tl*64 + f] = *(const float4*)&x1[xb + (size_t)(tb+tl)*D_ + d0 + f];
            *(float4*)&x2s[tl*64 + f] = *(const float4*)&x2[xb + (size_t)(tb+tl)*D_ + d0 + f];
            *(float4*)&w2s[tl*64 + f] = *(const float4*)&w2[(size_t)(tb+tl)*U_ + f];
            *(float4*)&w3s[tl*64 + f] = *(const float4*)&w3[(size_t)(tb+tl)*U_ + f];
        }
        __syncthreads();
        #pragma unroll 4
        for (int t = 0; t < TC_; ++t) {
            float4 a1 = *(const float4*)&x1s[t*64 + td*4];
            float4 a2 = *(const float4*)&x2s[t*64 + td*4];
            float4 c2 = *(const float4*)&w2s[t*64 + tu*4];
            float4 c3 = *(const float4*)&w3s[t*64 + tu*4];
            float a1v[4] = {a1.x,a1.y,a1.z,a1.w};
            float a2v[4] = {a2.x,a2.y,a2.z,a2.w};
            float c2v[4] = {c2.x,c2.y,c2.z,c2.w};
            float c3v[4] = {c3.x,c3.y,c3.z,c3.w};
            #pragma unroll
            for (int i = 0; i < 4; ++i)
                #pragma unroll
                for (int j = 0; j < 4; ++j) {
                    accM1[i][j] += a1v[i]*c3v[j];
                    accM1[i][j] += a2v[i]*c2v[j];
                    accM2[i][j] += a1v[i]*c2v[j];
                    accM2[i][j] += a2v[i]*c3v[j];
                }
        }
        __syncthreads();
    }

    const size_t DU = (size_t)D_ * U_;
    #pragma unroll
    for (int i = 0; i < 4; ++i) {
        size_t base = (((size_t)ts*B_ + b)*2)*DU + (size_t)(d0 + td*4 + i)*U_ + tu*4;
        float4 v1 = {accM1[i][0], accM1[i][1], accM1[i][2], accM1[i][3]};
        float4 v2 = {accM2[i][0], accM2[i][1], accM2[i][2], accM2[i][3]};
        *(float4*)&P[base]      = v1;
        *(float4*)&P[base + DU] = v2;
    }
}

// ---------------------------------------------------------------------------
// K1b: M1 = w1 + sum_ts P[ts][b][0];  M2 = w1 + sum_ts P[ts][b][1]
// ---------------------------------------------------------------------------
__global__ __launch_bounds__(256) void k1_combine(
    const float* __restrict__ P, const float* __restrict__ w1,
    float* __restrict__ M1, float* __restrict__ M2)
{
    const int n = blockIdx.x*256 + threadIdx.x;   // 0 .. B*D*U/4-1
    const int b = n >> 13;                        // D*U/4 = 8192
    const int r = n & 8191;
    const size_t du = (size_t)r * 4;
    const size_t DU = (size_t)D_ * U_;
    float4 w = *(const float4*)&w1[du];
    float4 s1 = w, s2 = w;
    #pragma unroll
    for (int ts = 0; ts < TS_; ++ts) {
        const float* Pb = P + (((size_t)ts*B_ + b)*2)*DU + du;
        float4 a = *(const float4*)&Pb[0];
        float4 c = *(const float4*)&Pb[DU];
        s1.x += a.x; s1.y += a.y; s1.z += a.z; s1.w += a.w;
        s2.x += c.x; s2.y += c.y; s2.z += c.z; s2.w += c.w;
    }
    *(float4*)&M1[(size_t)b*DU + du] = s1;
    *(float4*)&M2[(size_t)b*DU + du] = s2;
}

// ---------------------------------------------------------------------------
// K2: eij[br][b][t] = SR * sum_u tanh( sum_d x[b,t,d]*M[b,d,u] ) * we[u]
// block: (t-tile 64) x (b) x (branch); 256 threads; ~38 KiB LDS -> 4 blk/CU
// ---------------------------------------------------------------------------
#define TT_ 64
#define XPAD_ 69
__global__ __launch_bounds__(256, 4) void k2_eij(
    const float* __restrict__ x1, const float* __restrict__ x2,
    const float* __restrict__ M1, const float* __restrict__ M2,
    const float* __restrict__ we, float* __restrict__ eij)
{
    __shared__ float xT[64*XPAD_];   // [d][t] transposed, padded
    __shared__ float Ms[64*64];      // [d][u]
    __shared__ float wes[64];
    __shared__ float red[16*TT_];

    const int tt = blockIdx.x;       // 0..15
    const int b  = blockIdx.y;       // 0..31
    const int br = blockIdx.z;       // 0..1
    const float* x = br ? x2 : x1;
    const float* M = (br ? M2 : M1) + (size_t)b * D_ * U_;
    const int tid = threadIdx.x;
    const int tdl = tid & 15;        // t = tdl*4 + i
    const int tu  = tid >> 4;        // u = tu*4 + j
    if (tid < 64) wes[tid] = we[tid];

    float acc[4][4];
    #pragma unroll
    for (int i = 0; i < 4; ++i)
        #pragma unroll
        for (int j = 0; j < 4; ++j) acc[i][j] = 0.f;

    const size_t xb = (size_t)b*T_*D_ + (size_t)tt*TT_*D_;

    for (int c = 0; c < D_/64; ++c) {
        #pragma unroll
        for (int j = 0; j < 4; ++j) {
            int l  = j*256 + tid;        // 0..1023
            int tl = l >> 4;             // 0..63
            int f  = (l & 15) << 2;      // 0..60
            float4 v = *(const float4*)&x[xb + (size_t)tl*D_ + c*64 + f];
            xT[(f+0)*XPAD_ + tl] = v.x;
            xT[(f+1)*XPAD_ + tl] = v.y;
            xT[(f+2)*XPAD_ + tl] = v.z;
            xT[(f+3)*XPAD_ + tl] = v.w;
        }
        #pragma unroll
        for (int j = 0; j < 4; ++j) {
            int l  = j*256 + tid;
            int dl = l >> 4;
            int f  = (l & 15) << 2;
            *(float4*)&Ms[dl*64 + f] = *(const float4*)&M[(size_t)(c*64 + dl)*U_ + f];
        }
        __syncthreads();
        #pragma unroll 4
        for (int d = 0; d < 64; ++d) {
            float4 xv = *(const float4*)&xT[d*XPAD_ + tdl*4];
            float4 mv = *(const float4*)&Ms[d*64 + tu*4];
            float xvv[4] = {xv.x,xv.y,xv.z,xv.w};
            float mvv[4] = {mv.x,mv.y,mv.z,mv.w};
            #pragma unroll
            for (int i = 0; i < 4; ++i)
                #pragma unroll
                for (int j = 0; j < 4; ++j)
                    acc[i][j] += xvv[i]*mvv[j];
        }
        __syncthreads();
    }

    #pragma unroll
    for (int i = 0; i < 4; ++i) {
        float p = 0.f;
        #pragma unroll
        for (int j = 0; j < 4; ++j)
            p += tanhf(acc[i][j]) * wes[tu*4 + j];
        red[tu*TT_ + tdl*4 + i] = p;
    }
    __syncthreads();
    if (tid < TT_) {
        float s = 0.f;
        #pragma unroll
        for (int q = 0; q < 16; ++q) s += red[q*TT_ + tid];
        eij[((size_t)br*B_ + b)*T_ + tt*TT_ + tid] = SR_ * s;
    }
}

// ---------------------------------------------------------------------------
// K45: fused softmax + scale. Each block redundantly computes the softmax
// normalization for its (br,b) slab (4 KB of eij), then scales a 64-t chunk.
//   ww = exp(e-m)/(sum + eps*exp(-m));  out[br][b,t,d] = x[b,t,d]*ww[t]
// ---------------------------------------------------------------------------
__global__ __launch_bounds__(256) void k45_scale(
    const float* __restrict__ x1, const float* __restrict__ x2,
    const float* __restrict__ eij, float* __restrict__ out)
{
    __shared__ float sdata[256];
    __shared__ float wws[T_];

    const int tt = blockIdx.x;       // 0..15 : t-chunk of 64
    const int b  = blockIdx.y;       // 0..31
    const int br = blockIdx.z;       // 0..1
    const int tid = threadIdx.x;
    const float* e = eij + ((size_t)br*B_ + b) * T_;

    float v[4];
    float m = -1e30f;
    #pragma unroll
    for (int i = 0; i < 4; ++i) { v[i] = e[tid + i*256]; m = fmaxf(m, v[i]); }
    sdata[tid] = m; __syncthreads();
    for (int s = 128; s > 0; s >>= 1) {
        if (tid < s) sdata[tid] = fmaxf(sdata[tid], sdata[tid+s]);
        __syncthreads();
    }
    m = sdata[0]; __syncthreads();
    float ssum = 0.f;
    #pragma unroll
    for (int i = 0; i < 4; ++i) { v[i] = expf(v[i] - m); ssum += v[i]; }
    sdata[tid] = ssum; __syncthreads();
    for (int s = 128; s > 0; s >>= 1) {
        if (tid < s) sdata[tid] += sdata[tid+s];
        __syncthreads();
    }
    const float inv = 1.0f / (sdata[0] + EPS_ * expf(-m));
    #pragma unroll
    for (int i = 0; i < 4; ++i) wws[tid + i*256] = v[i] * inv;
    __syncthreads();

    // scale: t in [tt*64, tt*64+64), all d. 64*128 float4 = 8192; 32/thread.
    const float* x = br ? x2 : x1;
    const size_t xb4 = ((size_t)b*T_ + (size_t)tt*64) * (D_/4);
    float* o = out + (size_t)br*B_*T_*D_;
    #pragma unroll
    for (int k = 0; k < 32; ++k) {
        int idx = k*256 + tid;           // 0..8191
        int tl  = idx >> 7;              // 0..63 (128 float4 per t-row)
        float w = wws[tt*64 + tl];
        float4 xv = ((const float4*)x)[xb4 + idx];
        float4 ov = {xv.x*w, xv.y*w, xv.z*w, xv.w*w};
        ((float4*)o)[xb4 + idx] = ov;
    }
}

// ---------------------------------------------------------------------------
extern "C" void kernel_launch(void* const* d_in, const int* in_sizes, int n_in,
                              void* d_out, int out_size, void* d_ws, size_t ws_size,
                              hipStream_t stream)
{
    const float* x1 = (const float*)d_in[0];
    const float* x2 = (const float*)d_in[1];
    const float* w1 = (const float*)d_in[2];
    const float* w2 = (const float*)d_in[3];
    const float* w3 = (const float*)d_in[4];
    const float* we = (const float*)d_in[5];
    float* out = (float*)d_out;
    float* ws  = (float*)d_ws;

    // workspace layout (floats)
    float* P   = ws;                             // TS_*B_*2*D_*U_ = 8,388,608
    float* M1  = P   + (size_t)TS_*B_*2*D_*U_;   // 1,048,576
    float* M2  = M1  + (size_t)B_*D_*U_;         // 1,048,576
    float* eij = M2  + (size_t)B_*D_*U_;         // 65,536

    k1_partials<<<dim3(8, TS_, B_), 256, 0, stream>>>(x1, x2, w2, w3, P);
    k1_combine <<<dim3((B_*D_*U_/4 + 255)/256), 256, 0, stream>>>(P, w1, M1, M2);
    k2_eij     <<<dim3(T_/TT_, B_, 2), 256, 0, stream>>>(x1, x2, M1, M2, we, eij);
    k45_scale  <<<dim3(16, B_, 2), 256, 0, stream>>>(x1, x2, eij, out);
}